// Round 8
// baseline (224.906 us; speedup 1.0000x reference)
//
#include <hip/hip_runtime.h>
#include <hip/hip_bf16.h>
#include <math.h>

#define B_  16
#define T_  2048
#define C_  384
#define DK_ 64

typedef short bf16x8 __attribute__((ext_vector_type(8)));
typedef float f32x4  __attribute__((ext_vector_type(4)));
typedef unsigned short u16;
typedef unsigned int   u32;

// fp32 -> bf16 round-to-nearest-even (finite inputs)
__device__ __forceinline__ u16 f2bf(float f) {
  u32 u = __builtin_bit_cast(u32, f);
  u32 r = u + 0x7FFFu + ((u >> 16) & 1u);
  return (u16)(r >> 16);
}

__device__ __forceinline__ void gld_lds16(const void* g, void* l) {
  __builtin_amdgcn_global_load_lds(
      (const __attribute__((address_space(1))) void*)g,
      (__attribute__((address_space(3))) void*)l, 16, 0, 0);
}

__device__ __forceinline__ f32x4 mfma16(bf16x8 a, bf16x8 b, f32x4 c) {
  return __builtin_amdgcn_mfma_f32_16x16x32_bf16(a, b, c, 0, 0, 0);
}

// ---------------------------------------------------------------------------
// Kernel 1: build bf16 W^T [192][384] (rows 0..63 WQ*scale, 64..127 WK,
// 128..191 WV).  Plain layout — proj reads B-frags from L2.
// Scale for Q rows: (1/8)*log2(e) (exp2-domain softmax).
// ---------------------------------------------------------------------------
__global__ __launch_bounds__(256) void prep_w_k(
    const float* __restrict__ WQ, const float* __restrict__ WK,
    const float* __restrict__ WV, u16* __restrict__ wt) {
  int gi = blockIdx.x * 256 + threadIdx.x;
  if (gi >= 192 * 48) return;
  int n = gi / 48;
  int g = gi - n * 48;
  int k0 = g * 8;
  const float* W = (n < 64) ? WQ : ((n < 128) ? WK : WV);
  int   nn = n & 63;
  float sc = (n < 64) ? 0.18033688011112042f : 1.0f;
  bf16x8 o;
#pragma unroll
  for (int j = 0; j < 8; ++j)
    o[j] = (short)f2bf(W[(size_t)(k0 + j) * DK_ + nn] * sc);
  *(bf16x8*)(wt + (size_t)gi * 8) = o;
}

// ---------------------------------------------------------------------------
// Kernel 2 (UNDER TEST this round): fused QKV projection, LDS-free.
// B-frags straight from L2-hot wt.  256 thr / 4 waves; wave = 16 rows x 192
// cols; grid 512.  ALL outputs LINEAR (q,k,v [row][64]) — R1-flash convention.
// ---------------------------------------------------------------------------
__global__ __launch_bounds__(256) void proj_k(
    const float* __restrict__ x, const u16* __restrict__ wt,
    u16* __restrict__ qo, u16* __restrict__ ko, u16* __restrict__ vo) {
  int tid = threadIdx.x;
  int w = tid >> 6, lane = tid & 63, l15 = lane & 15, lg = lane >> 4;
  int row0 = (blockIdx.x * 4 + w) * 16;

  f32x4 acc[12];
#pragma unroll
  for (int i = 0; i < 12; ++i) acc[i] = (f32x4){0.f, 0.f, 0.f, 0.f};

  const float* xp0 = x + (size_t)(row0 + l15) * C_ + lg * 8;
#pragma unroll
  for (int ks = 0; ks < 12; ++ks) {
    float4 alo = *(const float4*)(xp0 + ks * 32);
    float4 ahi = *(const float4*)(xp0 + ks * 32 + 4);
    bf16x8 af;
    af[0] = (short)f2bf(alo.x); af[1] = (short)f2bf(alo.y);
    af[2] = (short)f2bf(alo.z); af[3] = (short)f2bf(alo.w);
    af[4] = (short)f2bf(ahi.x); af[5] = (short)f2bf(ahi.y);
    af[6] = (short)f2bf(ahi.z); af[7] = (short)f2bf(ahi.w);
#pragma unroll
    for (int nt = 0; nt < 12; ++nt) {
      bf16x8 bfg = *(const bf16x8*)(wt + (size_t)(nt * 16 + l15) * C_ + ks * 32 + lg * 8);
      acc[nt] = mfma16(af, bfg, acc[nt]);
    }
  }
#pragma unroll
  for (int nt = 0; nt < 12; ++nt) {
    int col = nt * 16 + l15;
    int c = col & 63;
#pragma unroll
    for (int r = 0; r < 4; ++r) {
      int row = row0 + lg * 4 + r;
      u16 val = f2bf(acc[nt][r]);
      if (col < 64)       qo[(size_t)row * DK_ + c] = val;
      else if (col < 128) ko[(size_t)row * DK_ + c] = val;
      else                vo[(size_t)row * DK_ + c] = val;
    }
  }
}

// ---------------------------------------------------------------------------
// Kernel 3 (CONTROL: byte-identical to Round-1 PASSING version).
// Causal flash attention.  One block = (batch b, q-tile of 64 rows).
// 4 waves x 16 q-rows.  KV tiles of 64.  exp2-domain online softmax.
// ---------------------------------------------------------------------------
__global__ __launch_bounds__(256) void flash_k(
    const u16* __restrict__ q, const u16* __restrict__ k,
    const u16* __restrict__ v, float* __restrict__ out) {
  __shared__ u16 ldsK[64 * 64];    // K tile  [kv][d], granule-swizzled (g^(kv&7))
  __shared__ u16 ldsVT[64 * 64];   // V^T tile [d][kv], swizzled ((d&7)^((d>>3)&7))
  __shared__ u16 ldsP[4 * 16 * 64];// per-wave P [16 q][64 kv], swizzled (row&7)

  int tid = threadIdx.x;
  int w = tid >> 6, lane = tid & 63, l15 = lane & 15, lg = lane >> 4;
  int bb = blockIdx.x & 15;
  int qt = 31 - (blockIdx.x >> 4);      // longest q-tiles first (LPT balance)
  int qrow0 = bb * T_ + qt * 64;

  // Q fragments (bf16, scale pre-folded): row = l15, k = lg*8 + j (+32 for slice 1)
  const u16* qp = q + (size_t)(qrow0 + w * 16 + l15) * DK_ + lg * 8;
  bf16x8 qf0 = *(const bf16x8*)qp;
  bf16x8 qf1 = *(const bf16x8*)(qp + 32);

  f32x4 o[4];
#pragma unroll
  for (int i = 0; i < 4; ++i) o[i] = (f32x4){0.f, 0.f, 0.f, 0.f};
  float m[4], lsum[4];
#pragma unroll
  for (int r = 0; r < 4; ++r) { m[r] = -INFINITY; lsum[r] = 0.f; }

  char* pbuf = (char*)ldsP + w * 2048;

  for (int t = 0; t <= qt; ++t) {
    __syncthreads();                     // prev-iter compute done before restage
    int kvb = bb * T_ + t * 64;

    // ---- stage K tile via global_load_lds, source XOR-swizzled, LDS linear
#pragma unroll
    for (int it = 0; it < 2; ++it) {
      int i = it * 256 + tid;
      int r = i >> 3, s = i & 7;
      gld_lds16(k + (size_t)(kvb + r) * DK_ + ((s ^ (r & 7)) * 8),
                (char*)ldsK + (it * 256 + w * 64) * 16);
    }
    // ---- stage V^T (reg transpose; u32 = {V[kv][d], V[kv+1][d]})
    {
      int kv = (tid >> 3) * 2;
      int d0 = (tid & 7) * 8;
      bf16x8 r0 = *(const bf16x8*)(v + (size_t)(kvb + kv) * DK_ + d0);
      bf16x8 r1 = *(const bf16x8*)(v + (size_t)(kvb + kv + 1) * DK_ + d0);
#pragma unroll
      for (int j = 0; j < 8; ++j) {
        int d = d0 + j;
        u32 val = (u32)(u16)r0[j] | ((u32)(u16)r1[j] << 16);
        int off = d * 128 + ((kv * 2) ^ ((((d & 7) ^ ((d >> 3) & 7))) << 4));
        *(u32*)((char*)ldsVT + off) = val;
      }
    }
    __syncthreads();

    // ---- S = Q K^T  (per wave: 16 q-rows x 64 kv)
    f32x4 sa[4];
#pragma unroll
    for (int nt = 0; nt < 4; ++nt) {
      int n = nt * 16 + l15;             // kv row in tile
      bf16x8 kb0 = *(const bf16x8*)((char*)ldsK + (n * 8 + ((lg) ^ (n & 7))) * 16);
      bf16x8 kb1 = *(const bf16x8*)((char*)ldsK + (n * 8 + ((4 + lg) ^ (n & 7))) * 16);
      sa[nt] = (f32x4){0.f, 0.f, 0.f, 0.f};
      sa[nt] = mfma16(qf0, kb0, sa[nt]);
      sa[nt] = mfma16(qf1, kb1, sa[nt]);
    }

    // ---- causal mask (diagonal tile only)
    if (t == qt) {
      int rowt = w * 16 + lg * 4;
#pragma unroll
      for (int nt = 0; nt < 4; ++nt) {
        int colt = nt * 16 + l15;
#pragma unroll
        for (int r = 0; r < 4; ++r)
          if (colt > rowt + r) sa[nt][r] = -INFINITY;
      }
    }

    // ---- online softmax (exp2 domain); rows live on 16-lane groups
#pragma unroll
    for (int r = 0; r < 4; ++r) {
      float mx = fmaxf(fmaxf(sa[0][r], sa[1][r]), fmaxf(sa[2][r], sa[3][r]));
      mx = fmaxf(mx, __shfl_xor(mx, 1));
      mx = fmaxf(mx, __shfl_xor(mx, 2));
      mx = fmaxf(mx, __shfl_xor(mx, 4));
      mx = fmaxf(mx, __shfl_xor(mx, 8));
      float mn = fmaxf(m[r], mx);
      float al = exp2f(m[r] - mn);       // m=-inf first tile -> al=0
      m[r] = mn;
      float rs = 0.f;
#pragma unroll
      for (int nt = 0; nt < 4; ++nt) {
        float p = exp2f(sa[nt][r] - mn);
        sa[nt][r] = p;
        rs += p;
      }
      rs += __shfl_xor(rs, 1); rs += __shfl_xor(rs, 2);
      rs += __shfl_xor(rs, 4); rs += __shfl_xor(rs, 8);
      lsum[r] = lsum[r] * al + rs;
      o[0][r] *= al; o[1][r] *= al; o[2][r] *= al; o[3][r] *= al;
    }

    // ---- P -> bf16 -> per-wave LDS (pair-packed u32, even lanes store)
#pragma unroll
    for (int nt = 0; nt < 4; ++nt) {
#pragma unroll
      for (int r = 0; r < 4; ++r) {
        float pv = sa[nt][r];
        float po = __shfl_xor(pv, 1);
        u32 pk = (lane & 1) ? ((u32)f2bf(po) | ((u32)f2bf(pv) << 16))
                            : ((u32)f2bf(pv) | ((u32)f2bf(po) << 16));
        if (!(lane & 1)) {
          int row = lg * 4 + r;
          int off = row * 128 + ((((nt * 16 + l15) & ~1) * 2) ^ ((row & 7) << 4));
          *(u32*)(pbuf + off) = pk;
        }
      }
    }

    // ---- O += P V   (A-frags from pbuf, B-frags from swizzled V^T)
    bf16x8 pf0, pf1;
    {
      int row = l15;
      int sw = (row & 7) << 4;
      pf0 = *(const bf16x8*)(pbuf + row * 128 + (((lg * 8) * 2) ^ sw));
      pf1 = *(const bf16x8*)(pbuf + row * 128 + (((32 + lg * 8) * 2) ^ sw));
    }
#pragma unroll
    for (int dt = 0; dt < 4; ++dt) {
      int d = dt * 16 + l15;
      int swv = ((d & 7) ^ ((d >> 3) & 7)) << 4;
      bf16x8 vf0 = *(const bf16x8*)((char*)ldsVT + d * 128 + (((lg * 8) * 2) ^ swv));
      bf16x8 vf1 = *(const bf16x8*)((char*)ldsVT + d * 128 + (((32 + lg * 8) * 2) ^ swv));
      o[dt] = mfma16(pf0, vf0, o[dt]);
      o[dt] = mfma16(pf1, vf1, o[dt]);
    }
  }

  // ---- epilogue: normalize, fp32 store
  float rl[4];
#pragma unroll
  for (int r = 0; r < 4; ++r) rl[r] = 1.f / lsum[r];
#pragma unroll
  for (int dt = 0; dt < 4; ++dt)
#pragma unroll
    for (int r = 0; r < 4; ++r)
      out[(size_t)(qrow0 + w * 16 + lg * 4 + r) * DK_ + dt * 16 + l15] =
          o[dt][r] * rl[r];
}

// ---------------------------------------------------------------------------
extern "C" void kernel_launch(void* const* d_in, const int* in_sizes, int n_in,
                              void* d_out, int out_size, void* d_ws, size_t ws_size,
                              hipStream_t stream) {
  const float* x  = (const float*)d_in[0];
  const float* WQ = (const float*)d_in[1];
  const float* WK = (const float*)d_in[2];
  const float* WV = (const float*)d_in[3];
  float* out = (float*)d_out;

  char* ws = (char*)d_ws;
  u16* qb = (u16*)(ws);
  u16* kb = (u16*)(ws + ((size_t)4 << 20));
  u16* vb = (u16*)(ws + ((size_t)8 << 20));
  u16* wt = (u16*)(ws + ((size_t)12 << 20));

  prep_w_k<<<36, 256, 0, stream>>>(WQ, WK, WV, wt);
  proj_k<<<512, 256, 0, stream>>>(x, wt, qb, kb, vb);
  flash_k<<<512, 256, 0, stream>>>(qb, kb, vb, out);
}

// Round 12
// 189.109 us; speedup vs baseline: 1.1893x; 1.1893x over previous
//
#include <hip/hip_runtime.h>
#include <hip/hip_bf16.h>
#include <math.h>

#define B_  16
#define T_  2048
#define C_  384
#define DK_ 64

typedef short bf16x8 __attribute__((ext_vector_type(8)));
typedef float f32x4  __attribute__((ext_vector_type(4)));
typedef unsigned short u16;
typedef unsigned int   u32;

// fp32 -> bf16 round-to-nearest-even (finite inputs)
__device__ __forceinline__ u16 f2bf(float f) {
  u32 u = __builtin_bit_cast(u32, f);
  u32 r = u + 0x7FFFu + ((u >> 16) & 1u);
  return (u16)(r >> 16);
}

__device__ __forceinline__ void gld_lds16(const void* g, void* l) {
  __builtin_amdgcn_global_load_lds(
      (const __attribute__((address_space(1))) void*)g,
      (__attribute__((address_space(3))) void*)l, 16, 0, 0);
}

__device__ __forceinline__ f32x4 mfma16(bf16x8 a, bf16x8 b, f32x4 c) {
  return __builtin_amdgcn_mfma_f32_16x16x32_bf16(a, b, c, 0, 0, 0);
}

// ---------------------------------------------------------------------------
// Kernel 1 (verified): bf16 W^T [192][384]; rows 0..63 WQ*(log2e/8), then WK, WV.
// ---------------------------------------------------------------------------
__global__ __launch_bounds__(256) void prep_w_k(
    const float* __restrict__ WQ, const float* __restrict__ WK,
    const float* __restrict__ WV, u16* __restrict__ wt) {
  int gi = blockIdx.x * 256 + threadIdx.x;
  if (gi >= 192 * 48) return;
  int n = gi / 48;
  int g = gi - n * 48;
  int k0 = g * 8;
  const float* W = (n < 64) ? WQ : ((n < 128) ? WK : WV);
  int   nn = n & 63;
  float sc = (n < 64) ? 0.18033688011112042f : 1.0f;
  bf16x8 o;
#pragma unroll
  for (int j = 0; j < 8; ++j)
    o[j] = (short)f2bf(W[(size_t)(k0 + j) * DK_ + nn] * sc);
  *(bf16x8*)(wt + (size_t)gi * 8) = o;
}

// ---------------------------------------------------------------------------
// Kernel 2: fused QKV projection, LDS-free, COL-SPLIT x2 (anti-spill).
// Wave = 16 rows x 96 cols (acc[6] = 24 VGPR); ks loop unroll-limited to 2.
// Grid 1024 (= 512 row-groups x 2 col-halves) -> 16 waves/CU.
// Outputs LINEAR [row][64] (R8-verified store semantics).
// ---------------------------------------------------------------------------
__global__ __launch_bounds__(256) void proj_k(
    const float* __restrict__ x, const u16* __restrict__ wt,
    u16* __restrict__ qo, u16* __restrict__ ko, u16* __restrict__ vo) {
  int tid = threadIdx.x;
  int w = tid >> 6, lane = tid & 63, l15 = lane & 15, lg = lane >> 4;
  int half = blockIdx.x & 1;
  int row0 = ((blockIdx.x >> 1) * 4 + w) * 16;
  int cbase = half * 96;

  f32x4 acc[6];
#pragma unroll
  for (int i = 0; i < 6; ++i) acc[i] = (f32x4){0.f, 0.f, 0.f, 0.f};

  const float* xp0 = x + (size_t)(row0 + l15) * C_ + lg * 8;
  const u16*   wb  = wt + (size_t)(cbase + l15) * C_ + lg * 8;
#pragma unroll 2
  for (int ks = 0; ks < 12; ++ks) {
    float4 alo = *(const float4*)(xp0 + ks * 32);
    float4 ahi = *(const float4*)(xp0 + ks * 32 + 4);
    bf16x8 af;
    af[0] = (short)f2bf(alo.x); af[1] = (short)f2bf(alo.y);
    af[2] = (short)f2bf(alo.z); af[3] = (short)f2bf(alo.w);
    af[4] = (short)f2bf(ahi.x); af[5] = (short)f2bf(ahi.y);
    af[6] = (short)f2bf(ahi.z); af[7] = (short)f2bf(ahi.w);
#pragma unroll
    for (int nt = 0; nt < 6; ++nt) {
      bf16x8 bfg = *(const bf16x8*)(wb + (size_t)nt * 16 * C_ + ks * 32);
      acc[nt] = mfma16(af, bfg, acc[nt]);
    }
  }
#pragma unroll
  for (int nt = 0; nt < 6; ++nt) {
    int col = cbase + nt * 16 + l15;
#pragma unroll
    for (int r = 0; r < 4; ++r) {
      int row = row0 + lg * 4 + r;
      u16 val = f2bf(acc[nt][r]);
      if (col < 64)       qo[(size_t)row * DK_ + col] = val;
      else if (col < 128) ko[(size_t)row * DK_ + (col - 64)] = val;
      else                vo[(size_t)row * DK_ + (col - 128)] = val;
    }
  }
}

// ---------------------------------------------------------------------------
// Kernel 3: causal flash attention, KV-SPLIT across blocks.
// Block = (batch bb, q-tile qt, split s); processes tiles t = s, s+S, ... <= qt
// with the R1-VERIFIED data path (staging/MFMA/softmax/P-pack unchanged).
// Epilogue stores unnormalized O + (m, lsum) partials; merge_k combines.
// ---------------------------------------------------------------------------
__global__ __launch_bounds__(256) void flash_k(
    const u16* __restrict__ q, const u16* __restrict__ k,
    const u16* __restrict__ v, float* __restrict__ pO,
    float* __restrict__ pML, int lgS) {
  __shared__ u16 ldsK[64 * 64];    // K tile  [kv][d], granule-swizzled (g^(kv&7))
  __shared__ u16 ldsVT[64 * 64];   // V^T tile [d][kv], swizzled ((d&7)^((d>>3)&7))
  __shared__ u16 ldsP[4 * 16 * 64];// per-wave P [16 q][64 kv], swizzled (row&7)

  int Sv = 1 << lgS;
  int s   = blockIdx.x & (Sv - 1);
  int idx = blockIdx.x >> lgS;          // 0..511
  int tid = threadIdx.x;
  int w = tid >> 6, lane = tid & 63, l15 = lane & 15, lg = lane >> 4;
  int bb = idx & 15;
  int qt = 31 - (idx >> 4);             // longest q-tiles first (LPT)
  int qrow0 = bb * T_ + qt * 64;

  // Q fragments (bf16, scale pre-folded): row = l15, k = lg*8 + j (+32)
  const u16* qp = q + (size_t)(qrow0 + w * 16 + l15) * DK_ + lg * 8;
  bf16x8 qf0 = *(const bf16x8*)qp;
  bf16x8 qf1 = *(const bf16x8*)(qp + 32);

  f32x4 o[4];
#pragma unroll
  for (int i = 0; i < 4; ++i) o[i] = (f32x4){0.f, 0.f, 0.f, 0.f};
  float m[4], lsum[4];
#pragma unroll
  for (int r = 0; r < 4; ++r) { m[r] = -INFINITY; lsum[r] = 0.f; }

  char* pbuf = (char*)ldsP + w * 2048;

  for (int t = s; t <= qt; t += Sv) {
    __syncthreads();                     // prev-iter compute done before restage
    int kvb = bb * T_ + t * 64;

    // ---- stage K tile via global_load_lds, source XOR-swizzled, LDS linear
#pragma unroll
    for (int it = 0; it < 2; ++it) {
      int i = it * 256 + tid;
      int r = i >> 3, ss = i & 7;
      gld_lds16(k + (size_t)(kvb + r) * DK_ + ((ss ^ (r & 7)) * 8),
                (char*)ldsK + (it * 256 + w * 64) * 16);
    }
    // ---- stage V^T (reg transpose; u32 = {V[kv][d], V[kv+1][d]})
    {
      int kv = (tid >> 3) * 2;
      int d0 = (tid & 7) * 8;
      bf16x8 r0 = *(const bf16x8*)(v + (size_t)(kvb + kv) * DK_ + d0);
      bf16x8 r1 = *(const bf16x8*)(v + (size_t)(kvb + kv + 1) * DK_ + d0);
#pragma unroll
      for (int j = 0; j < 8; ++j) {
        int d = d0 + j;
        u32 val = (u32)(u16)r0[j] | ((u32)(u16)r1[j] << 16);
        int off = d * 128 + ((kv * 2) ^ ((((d & 7) ^ ((d >> 3) & 7))) << 4));
        *(u32*)((char*)ldsVT + off) = val;
      }
    }
    __syncthreads();

    // ---- S = Q K^T  (per wave: 16 q-rows x 64 kv)
    f32x4 sa[4];
#pragma unroll
    for (int nt = 0; nt < 4; ++nt) {
      int n = nt * 16 + l15;             // kv row in tile
      bf16x8 kb0 = *(const bf16x8*)((char*)ldsK + (n * 8 + ((lg) ^ (n & 7))) * 16);
      bf16x8 kb1 = *(const bf16x8*)((char*)ldsK + (n * 8 + ((4 + lg) ^ (n & 7))) * 16);
      sa[nt] = (f32x4){0.f, 0.f, 0.f, 0.f};
      sa[nt] = mfma16(qf0, kb0, sa[nt]);
      sa[nt] = mfma16(qf1, kb1, sa[nt]);
    }

    // ---- causal mask (diagonal tile only)
    if (t == qt) {
      int rowt = w * 16 + lg * 4;
#pragma unroll
      for (int nt = 0; nt < 4; ++nt) {
        int colt = nt * 16 + l15;
#pragma unroll
        for (int r = 0; r < 4; ++r)
          if (colt > rowt + r) sa[nt][r] = -INFINITY;
      }
    }

    // ---- online softmax (exp2 domain); rows live on 16-lane groups
#pragma unroll
    for (int r = 0; r < 4; ++r) {
      float mx = fmaxf(fmaxf(sa[0][r], sa[1][r]), fmaxf(sa[2][r], sa[3][r]));
      mx = fmaxf(mx, __shfl_xor(mx, 1));
      mx = fmaxf(mx, __shfl_xor(mx, 2));
      mx = fmaxf(mx, __shfl_xor(mx, 4));
      mx = fmaxf(mx, __shfl_xor(mx, 8));
      float mn = fmaxf(m[r], mx);
      float al = exp2f(m[r] - mn);       // m=-inf first tile -> al=0
      m[r] = mn;
      float rs = 0.f;
#pragma unroll
      for (int nt = 0; nt < 4; ++nt) {
        float p = exp2f(sa[nt][r] - mn);
        sa[nt][r] = p;
        rs += p;
      }
      rs += __shfl_xor(rs, 1); rs += __shfl_xor(rs, 2);
      rs += __shfl_xor(rs, 4); rs += __shfl_xor(rs, 8);
      lsum[r] = lsum[r] * al + rs;
      o[0][r] *= al; o[1][r] *= al; o[2][r] *= al; o[3][r] *= al;
    }

    // ---- P -> bf16 -> per-wave LDS (pair-packed u32, even lanes store)
#pragma unroll
    for (int nt = 0; nt < 4; ++nt) {
#pragma unroll
      for (int r = 0; r < 4; ++r) {
        float pv = sa[nt][r];
        float po = __shfl_xor(pv, 1);
        u32 pk = (lane & 1) ? ((u32)f2bf(po) | ((u32)f2bf(pv) << 16))
                            : ((u32)f2bf(pv) | ((u32)f2bf(po) << 16));
        if (!(lane & 1)) {
          int row = lg * 4 + r;
          int off = row * 128 + ((((nt * 16 + l15) & ~1) * 2) ^ ((row & 7) << 4));
          *(u32*)(pbuf + off) = pk;
        }
      }
    }

    // ---- O += P V   (A-frags from pbuf, B-frags from swizzled V^T)
    bf16x8 pf0, pf1;
    {
      int row = l15;
      int sw = (row & 7) << 4;
      pf0 = *(const bf16x8*)(pbuf + row * 128 + (((lg * 8) * 2) ^ sw));
      pf1 = *(const bf16x8*)(pbuf + row * 128 + (((32 + lg * 8) * 2) ^ sw));
    }
#pragma unroll
    for (int dt = 0; dt < 4; ++dt) {
      int d = dt * 16 + l15;
      int swv = ((d & 7) ^ ((d >> 3) & 7)) << 4;
      bf16x8 vf0 = *(const bf16x8*)((char*)ldsVT + d * 128 + (((lg * 8) * 2) ^ swv));
      bf16x8 vf1 = *(const bf16x8*)((char*)ldsVT + d * 128 + (((32 + lg * 8) * 2) ^ swv));
      o[dt] = mfma16(pf0, vf0, o[dt]);
      o[dt] = mfma16(pf1, vf1, o[dt]);
    }
  }

  // ---- partial epilogue: store unnormalized O and (m, lsum) per row
  float* po = pO + (((size_t)idx << lgS) + s) * 4096;
#pragma unroll
  for (int dt = 0; dt < 4; ++dt)
#pragma unroll
    for (int r = 0; r < 4; ++r)
      po[(w * 16 + lg * 4 + r) * 64 + dt * 16 + l15] = o[dt][r];
  if (l15 == 0) {
    float* pm = pML + (((size_t)idx << lgS) + s) * 128;
#pragma unroll
    for (int r = 0; r < 4; ++r) {
      pm[w * 16 + lg * 4 + r]      = m[r];
      pm[64 + w * 16 + lg * 4 + r] = lsum[r];
    }
  }
}

// ---------------------------------------------------------------------------
// Kernel 4: merge S partials per (batch, q-tile).  Block = idx (0..511),
// thread = (row = tid>>2, 16-col group = tid&3).
// ---------------------------------------------------------------------------
__global__ __launch_bounds__(256) void merge_k(
    const float* __restrict__ pO, const float* __restrict__ pML,
    float* __restrict__ out, int lgS) {
  int Sv = 1 << lgS;
  int idx = blockIdx.x;
  int bb = idx & 15, qt = 31 - (idx >> 4);
  int row = threadIdx.x >> 2, cg = threadIdx.x & 3;

  const float* pm = pML + ((size_t)idx << lgS) * 128;
  float mstar = -INFINITY;
  for (int s = 0; s < Sv; ++s) mstar = fmaxf(mstar, pm[s * 128 + row]);

  float lstar = 0.f;
  float acc[16];
#pragma unroll
  for (int c = 0; c < 16; ++c) acc[c] = 0.f;
  const float* po = pO + ((size_t)idx << lgS) * 4096 + row * 64 + cg * 16;
  for (int s = 0; s < Sv; ++s) {
    float wsc = exp2f(pm[s * 128 + row] - mstar);   // 0 for empty splits
    lstar += wsc * pm[s * 128 + 64 + row];
    const float* ps = po + (size_t)s * 4096;
#pragma unroll
    for (int c = 0; c < 16; ++c) acc[c] += wsc * ps[c];
  }
  float inv = 1.f / lstar;
  size_t orow = (size_t)(bb * T_ + qt * 64 + row) * DK_ + cg * 16;
#pragma unroll
  for (int c = 0; c < 16; ++c) out[orow + c] = acc[c] * inv;
}

// ---------------------------------------------------------------------------
extern "C" void kernel_launch(void* const* d_in, const int* in_sizes, int n_in,
                              void* d_out, int out_size, void* d_ws, size_t ws_size,
                              hipStream_t stream) {
  const float* x  = (const float*)d_in[0];
  const float* WQ = (const float*)d_in[1];
  const float* WK = (const float*)d_in[2];
  const float* WV = (const float*)d_in[3];
  float* out = (float*)d_out;

  char* ws = (char*)d_ws;
  u16* qb = (u16*)(ws);
  u16* kb = (u16*)(ws + ((size_t)4 << 20));
  u16* vb = (u16*)(ws + ((size_t)8 << 20));
  u16* wt = (u16*)(ws + ((size_t)12 << 20));

  // KV-split factor gated by workspace size (partials: 512*S*(4096+128) f32)
  size_t pbase = (size_t)16 << 20;
  int lgS = 2;
  if (ws_size < pbase + (size_t)512 * 4 * (4096 + 128) * 4) lgS = 1;
  if (ws_size < pbase + (size_t)512 * 2 * (4096 + 128) * 4) lgS = 0;
  size_t S = (size_t)1 << lgS;
  float* pO  = (float*)(ws + pbase);
  float* pML = (float*)(ws + pbase + (size_t)512 * S * 4096 * 4);

  prep_w_k<<<36, 256, 0, stream>>>(WQ, WK, WV, wt);
  proj_k<<<1024, 256, 0, stream>>>(x, wt, qb, kb, vb);
  flash_k<<<512 << lgS, 256, 0, stream>>>(qb, kb, vb, pO, pML, lgS);
  merge_k<<<512, 256, 0, stream>>>(pO, pML, out, lgS);
}